// Round 1
// baseline (491.535 us; speedup 1.0000x reference)
//
#include <hip/hip_runtime.h>

// Problem constants (match reference shapes)
#define B_ 2
#define N_ 8192
#define T_ 32
#define C_ 64
#define K_ 16
#define NB_ 4

__global__ __launch_bounds__(256) void geodcd_kernel(
    const float* __restrict__ z,      // (B, N, T, C)
    const int*   __restrict__ nidx,   // (N, K)
    const float* __restrict__ adj,    // (N, K)
    const float* __restrict__ bw,     // (NB, N, K)
    const float* __restrict__ cc,     // (C, NB)
    float*       __restrict__ out)    // (B, N, T, C)
{
    const int n   = blockIdx.x;
    const int tid = threadIdx.x;

    __shared__ float ew[K_][C_];   // edge weights for this node: [k][c], 4 KiB
    __shared__ int   idx_s[K_];

    if (tid < K_) idx_s[tid] = nidx[n * K_ + tid];

    // ew[k][c] = adj[n,k] * sum_b cc[c,b] * bw[b,n,k]
    for (int i = tid; i < K_ * C_; i += 256) {
        const int k = i >> 6;
        const int c = i & 63;
        float s = 0.f;
#pragma unroll
        for (int b = 0; b < NB_; ++b)
            s += cc[c * NB_ + b] * bw[(b * N_ + n) * K_ + k];
        ew[k][c] = s * adj[n * K_ + k];
    }
    __syncthreads();

    // Thread mapping: 16 lanes cover C=64 via float4; 16 t-groups.
    const int c4 = (tid & 15) * 4;
    const int t0 = tid >> 4;          // 0..15

    // Hoist this thread's weights into registers (16 x float4).
    float4 w[K_];
#pragma unroll
    for (int k = 0; k < K_; ++k)
        w[k] = *(const float4*)&ew[k][c4];

    // Neighbor tile base offsets (elements). Max ~33.5M fits in int32.
    int zoff[K_];
#pragma unroll
    for (int k = 0; k < K_; ++k)
        zoff[k] = idx_s[k] * (T_ * C_);

#pragma unroll
    for (int b = 0; b < B_; ++b) {
        const float* zb = z   + (size_t)b * (N_ * T_ * C_);
        float*       ob = out + (size_t)b * (N_ * T_ * C_) + n * (T_ * C_);
#pragma unroll
        for (int tt = 0; tt < 2; ++tt) {
            const int t = t0 + tt * 16;
            const int rowoff = t * C_ + c4;
            float4 acc = make_float4(0.f, 0.f, 0.f, 0.f);
#pragma unroll
            for (int k = 0; k < K_; ++k) {
                const float4 v = *(const float4*)&zb[zoff[k] + rowoff];
                acc.x += v.x * w[k].x;
                acc.y += v.y * w[k].y;
                acc.z += v.z * w[k].z;
                acc.w += v.w * w[k].w;
            }
            // tanh(x) = 1 - 2/(exp(2x)+1); exact limits at +/-inf via expf under/overflow
            float4 r;
            r.x = 1.f - 2.f / (__expf(2.f * acc.x) + 1.f);
            r.y = 1.f - 2.f / (__expf(2.f * acc.y) + 1.f);
            r.z = 1.f - 2.f / (__expf(2.f * acc.z) + 1.f);
            r.w = 1.f - 2.f / (__expf(2.f * acc.w) + 1.f);
            *(float4*)&ob[rowoff] = r;
        }
    }
}

extern "C" void kernel_launch(void* const* d_in, const int* in_sizes, int n_in,
                              void* d_out, int out_size, void* d_ws, size_t ws_size,
                              hipStream_t stream) {
    const float* z    = (const float*)d_in[0];
    const int*   nidx = (const int*)  d_in[1];
    const float* adj  = (const float*)d_in[2];
    const float* bw   = (const float*)d_in[3];
    const float* cc   = (const float*)d_in[4];
    float*       out  = (float*)d_out;

    geodcd_kernel<<<N_, 256, 0, stream>>>(z, nidx, adj, bw, cc, out);
}